// Round 1
// baseline (782.772 us; speedup 1.0000x reference)
//
#include <hip/hip_runtime.h>
#include <math.h>

typedef __attribute__((ext_vector_type(4))) float f32x4;
typedef __attribute__((ext_vector_type(8))) __bf16 bf16x8;
typedef __attribute__((ext_vector_type(8))) short short8;

#define DEV __device__ __forceinline__

DEV short f2bfs(float f) {
    unsigned u = __builtin_bit_cast(unsigned, f);
    unsigned r = (u + 0x7FFFu + ((u >> 16) & 1u)) >> 16;   // RNE
    return (short)r;
}

DEV f32x4 mfma16(bf16x8 a, bf16x8 b, f32x4 c) {
    return __builtin_amdgcn_mfma_f32_16x16x32_bf16(a, b, c, 0, 0, 0);
}

DEV void gload_lds16(const void* g, void* l) {
    __builtin_amdgcn_global_load_lds((const __attribute__((address_space(1))) void*)g,
                                     (__attribute__((address_space(3))) void*)l, 16, 0, 0);
}

// ---------------------------------------------------------------------------
// Weight convert+transpose: Win f32 [Kd,Nd] -> Wout bf16 [Nd,Kd]
// ---------------------------------------------------------------------------
__global__ __launch_bounds__(256) void wtrans(const float* __restrict__ Win,
                                              short* __restrict__ Wout,
                                              int Kd, int Nd) {
    __shared__ float Tt[32][33];
    const int tx = threadIdx.x & 31, ty = threadIdx.x >> 5;  // ty 0..7
    const int k0 = blockIdx.y * 32, n0 = blockIdx.x * 32;
#pragma unroll
    for (int rr = 0; rr < 4; ++rr) {
        int k = ty * 4 + rr;
        Tt[k][tx] = Win[(size_t)(k0 + k) * Nd + n0 + tx];
    }
    __syncthreads();
#pragma unroll
    for (int rr = 0; rr < 4; ++rr) {
        int n = ty * 4 + rr;
        Wout[(size_t)(n0 + n) * Kd + k0 + tx] = f2bfs(Tt[tx][n]);
    }
}

// f32 -> bf16 elementwise (4 per thread)
__global__ __launch_bounds__(256) void conv_bf16(const float* __restrict__ X,
                                                 short* __restrict__ Y, int n4) {
    int i = blockIdx.x * 256 + threadIdx.x;
    if (i < n4) {
        float4 v = ((const float4*)X)[i];
        short4 o;
        o.x = f2bfs(v.x); o.y = f2bfs(v.y); o.z = f2bfs(v.z); o.w = f2bfs(v.w);
        ((short4*)Y)[i] = o;
    }
}

// ---------------------------------------------------------------------------
// GEMM: A bf16 [M,K] row-major, BT bf16 [N,K] row-major, + bias.
// EPI 0: f32 out [M,N].  EPI 1: bf16 heads [B,H,T,64] (T=1024, H=16).
// EPI 2: exact-GELU bf16 out [M,N].
// m97 structure: 128x128 tile, BK=32, global_load_lds width 16.
// ---------------------------------------------------------------------------
template <int EPI>
__global__ __launch_bounds__(256) void gemm_bt(const short* __restrict__ A,
                                               const short* __restrict__ BT,
                                               const float* __restrict__ bias,
                                               void* __restrict__ Cout,
                                               int M, int N, int K) {
    __shared__ __align__(16) short As[128 * 32];
    __shared__ __align__(16) short Bs[128 * 32];
    const int tid = threadIdx.x, lane = tid & 63, w = tid >> 6;
    const int m0 = blockIdx.y * 128, n0 = blockIdx.x * 128;
    const int wm = (w & 1) * 64, wn = (w >> 1) * 64;
    const int rl = lane & 15, rg = lane >> 4;
    f32x4 acc[4][4] = {};
    const char* Ab = (const char*)A;
    const char* Bb = (const char*)BT;

    for (int k0 = 0; k0 < K; k0 += 32) {
        __syncthreads();
#pragma unroll
        for (int rS = 0; rS < 2; ++rS) {
            int lo = w * 2048 + rS * 1024 + lane * 16;  // byte offset in tile
            int row = lo >> 6, kb = lo & 63;            // 64 B per row (32 bf16)
            gload_lds16(Ab + ((size_t)(m0 + row) * K + k0) * 2 + kb,
                        (char*)As + (w * 2048 + rS * 1024));
            gload_lds16(Bb + ((size_t)(n0 + row) * K + k0) * 2 + kb,
                        (char*)Bs + (w * 2048 + rS * 1024));
        }
        __syncthreads();
        bf16x8 af[4], bfr[4];
#pragma unroll
        for (int i = 0; i < 4; i++)
            af[i] = *(const bf16x8*)(As + (wm + i * 16 + rl) * 32 + rg * 8);
#pragma unroll
        for (int j = 0; j < 4; j++)
            bfr[j] = *(const bf16x8*)(Bs + (wn + j * 16 + rl) * 32 + rg * 8);
#pragma unroll
        for (int i = 0; i < 4; i++)
#pragma unroll
            for (int j = 0; j < 4; j++) acc[i][j] = mfma16(af[i], bfr[j], acc[i][j]);
    }

#pragma unroll
    for (int i = 0; i < 4; i++) {
#pragma unroll
        for (int j = 0; j < 4; j++) {
#pragma unroll
            for (int r = 0; r < 4; r++) {
                int gm = m0 + wm + i * 16 + rg * 4 + r;
                int gn = n0 + wn + j * 16 + rl;
                float v = acc[i][j][r] + bias[gn];
                if (EPI == 0) {
                    ((float*)Cout)[(size_t)gm * N + gn] = v;
                } else if (EPI == 1) {
                    int b = gm >> 10, t = gm & 1023, h = gn >> 6, d = gn & 63;
                    ((short*)Cout)[(((size_t)(b * 16 + h) * 1024 + t) * 64) + d] = f2bfs(v);
                } else {
                    float g = 0.5f * v * (1.0f + erff(v * 0.70710678118654752f));
                    ((short*)Cout)[(size_t)gm * N + gn] = f2bfs(g);
                }
            }
        }
    }
}

// ---------------------------------------------------------------------------
// V [bh][TK][64] -> VT [bh][64][TK]
// ---------------------------------------------------------------------------
__global__ __launch_bounds__(256) void transpose_v(const short* __restrict__ V,
                                                   short* __restrict__ VT, int TKn) {
    __shared__ __align__(16) short Tt[64][72];
    const int tid = threadIdx.x;
    const int bh = blockIdx.y;
    const int k0 = blockIdx.x * 64;
    const short* srcp = V + (size_t)bh * TKn * 64;
    short* dstp = VT + (size_t)bh * 64 * TKn;
#pragma unroll
    for (int rr = 0; rr < 2; ++rr) {
        int idx = tid + rr * 256;
        int key = idx >> 3, dg = idx & 7;
        *(short8*)(&Tt[key][dg * 8]) =
            *(const short8*)(srcp + (size_t)(k0 + key) * 64 + dg * 8);
    }
    __syncthreads();
#pragma unroll
    for (int rr = 0; rr < 2; ++rr) {
        int idx = tid + rr * 256;
        int d = idx >> 3, kg = idx & 7;
        short8 v;
#pragma unroll
        for (int jj = 0; jj < 8; ++jj) v[jj] = Tt[kg * 8 + jj][d];
        *(short8*)(dstp + (size_t)d * TKn + k0 + kg * 8) = v;
    }
}

// ---------------------------------------------------------------------------
// Flash attention: Qh [bh][1024][64], Kh [bh][TK][64], VTh [bh][64][TK] (bf16)
// Out bf16 [B,1024,1024]. Block = (b,h,64 Q rows), 4 waves x 16 rows.
// ---------------------------------------------------------------------------
template <bool CAUSAL>
__global__ __launch_bounds__(256) void attn_fused(const short* __restrict__ Qh,
                                                  const short* __restrict__ Kh,
                                                  const short* __restrict__ VTh,
                                                  short* __restrict__ Out, int TKn) {
    __shared__ __align__(16) short Ks[32 * 72];       // [key][d] pad 64->72
    __shared__ __align__(16) short Vts[64 * 40];      // [d][key] pad 32->40
    __shared__ __align__(16) short Ps[4 * 16 * 40];   // per-wave P, pad 32->40
    const int tid = threadIdx.x, lane = tid & 63, w = tid >> 6;
    const int rl = lane & 15, rg = lane >> 4;
    const int bh = blockIdx.y, b = bh >> 4, h = bh & 15;
    const int q0 = blockIdx.x * 64;
    const size_t qbase = (size_t)bh * 1024 * 64;
    const size_t kbase = (size_t)bh * (size_t)TKn * 64;

    bf16x8 qf[2];
    {
        int qrow = q0 + w * 16 + rl;
        qf[0] = *(const bf16x8*)(Qh + qbase + (size_t)qrow * 64 + rg * 8);
        qf[1] = *(const bf16x8*)(Qh + qbase + (size_t)qrow * 64 + 32 + rg * 8);
    }
    f32x4 o[4] = {};
    float mrow[4] = {-1e30f, -1e30f, -1e30f, -1e30f};
    float lrow[4] = {0.f, 0.f, 0.f, 0.f};

    const int nkt = CAUSAL ? (q0 >> 5) + 2 : (TKn >> 5);
    for (int kt = 0; kt < nkt; ++kt) {
        __syncthreads();
        {
            int key = tid >> 3, dg = tid & 7;
            *(bf16x8*)(Ks + key * 72 + dg * 8) =
                *(const bf16x8*)(Kh + kbase + (size_t)(kt * 32 + key) * 64 + dg * 8);
            int d = tid >> 2, kg = tid & 3;
            *(bf16x8*)(Vts + d * 40 + kg * 8) =
                *(const bf16x8*)(VTh + kbase + (size_t)d * TKn + kt * 32 + kg * 8);
        }
        __syncthreads();
        f32x4 s[2];
#pragma unroll
        for (int ch = 0; ch < 2; ++ch) {
            f32x4 z = {};
            bf16x8 kb0 = *(const bf16x8*)(Ks + (ch * 16 + rl) * 72 + rg * 8);
            bf16x8 kb1 = *(const bf16x8*)(Ks + (ch * 16 + rl) * 72 + 32 + rg * 8);
            z = mfma16(qf[0], kb0, z);
            z = mfma16(qf[1], kb1, z);
            s[ch] = z;
        }
        float alpha[4];
        short* Pw = Ps + w * 640;
#pragma unroll
        for (int r = 0; r < 4; ++r) {
            float s0 = s[0][r] * 0.125f, s1 = s[1][r] * 0.125f;
            if (CAUSAL) {
                int qr = q0 + w * 16 + rg * 4 + r;
                if (kt * 32 + rl > qr) s0 = -1e30f;
                if (kt * 32 + 16 + rl > qr) s1 = -1e30f;
            }
            float mx = fmaxf(s0, s1);
            mx = fmaxf(mx, __shfl_xor(mx, 1));
            mx = fmaxf(mx, __shfl_xor(mx, 2));
            mx = fmaxf(mx, __shfl_xor(mx, 4));
            mx = fmaxf(mx, __shfl_xor(mx, 8));
            float mn = fmaxf(mrow[r], mx);
            float al = __expf(mrow[r] - mn);
            mrow[r] = mn;
            float p0 = __expf(s0 - mn), p1 = __expf(s1 - mn);
            float rs = p0 + p1;
            rs += __shfl_xor(rs, 1);
            rs += __shfl_xor(rs, 2);
            rs += __shfl_xor(rs, 4);
            rs += __shfl_xor(rs, 8);
            lrow[r] = lrow[r] * al + rs;
            alpha[r] = al;
            Pw[(rg * 4 + r) * 40 + rl] = f2bfs(p0);
            Pw[(rg * 4 + r) * 40 + 16 + rl] = f2bfs(p1);
        }
#pragma unroll
        for (int j = 0; j < 4; j++)
#pragma unroll
            for (int r = 0; r < 4; r++) o[j][r] *= alpha[r];
        // LDS round-trip: C-layout P -> A-operand layout (compiler inserts lgkm wait)
        bf16x8 pa = *(const bf16x8*)(Ps + w * 640 + rl * 40 + rg * 8);
#pragma unroll
        for (int j = 0; j < 4; j++) {
            bf16x8 vb = *(const bf16x8*)(Vts + (j * 16 + rl) * 40 + rg * 8);
            o[j] = mfma16(pa, vb, o[j]);
        }
    }
    float inv[4];
#pragma unroll
    for (int r = 0; r < 4; r++) inv[r] = 1.0f / lrow[r];
#pragma unroll
    for (int j = 0; j < 4; j++) {
#pragma unroll
        for (int r = 0; r < 4; r++) {
            int row = q0 + w * 16 + rg * 4 + r;
            int col = h * 64 + j * 16 + rl;
            Out[((size_t)b * 1024 + row) * 1024 + col] = f2bfs(o[j][r] * inv[r]);
        }
    }
}

// ---------------------------------------------------------------------------
// Fused residual add + LayerNorm over C=1024. Writes f32 (+optional bf16).
// ---------------------------------------------------------------------------
__global__ __launch_bounds__(256) void ln_fused(const float* __restrict__ X,
                                                const float* __restrict__ R,
                                                const float* __restrict__ gam,
                                                const float* __restrict__ bet,
                                                float* __restrict__ Yf,
                                                short* __restrict__ Yb) {
    const int row = blockIdx.x, tid = threadIdx.x;
    const int lane = tid & 63, w = tid >> 6;
    const float* xr = X + (size_t)row * 1024;
    const float* rr = R + (size_t)row * 1024;
    float4 xv = ((const float4*)xr)[tid];
    float4 rv = ((const float4*)rr)[tid];
    float v0 = xv.x + rv.x, v1 = xv.y + rv.y, v2 = xv.z + rv.z, v3 = xv.w + rv.w;
    float s = v0 + v1 + v2 + v3;
    float ss = v0 * v0 + v1 * v1 + v2 * v2 + v3 * v3;
#pragma unroll
    for (int off = 1; off < 64; off <<= 1) {
        s += __shfl_xor(s, off);
        ss += __shfl_xor(ss, off);
    }
    __shared__ float sred[4], ssred[4];
    if (lane == 0) { sred[w] = s; ssred[w] = ss; }
    __syncthreads();
    s = sred[0] + sred[1] + sred[2] + sred[3];
    ss = ssred[0] + ssred[1] + ssred[2] + ssred[3];
    float mu = s * (1.0f / 1024.0f);
    float var = ss * (1.0f / 1024.0f) - mu * mu;
    float rsq = rsqrtf(var + 1e-12f);
    float4 gv = ((const float4*)gam)[tid];
    float4 bv = ((const float4*)bet)[tid];
    float y0 = (v0 - mu) * rsq * gv.x + bv.x;
    float y1 = (v1 - mu) * rsq * gv.y + bv.y;
    float y2 = (v2 - mu) * rsq * gv.z + bv.z;
    float y3 = (v3 - mu) * rsq * gv.w + bv.w;
    float4 yo = {y0, y1, y2, y3};
    ((float4*)(Yf + (size_t)row * 1024))[tid] = yo;
    if (Yb) {
        short4 ob;
        ob.x = f2bfs(y0); ob.y = f2bfs(y1); ob.z = f2bfs(y2); ob.w = f2bfs(y3);
        ((short4*)(Yb + (size_t)row * 1024))[tid] = ob;
    }
}

// ---------------------------------------------------------------------------
extern "C" void kernel_launch(void* const* d_in, const int* in_sizes, int n_in,
                              void* d_out, int out_size, void* d_ws, size_t ws_size,
                              hipStream_t stream) {
    const float* src = (const float*)d_in[0];
    const float* dst = (const float*)d_in[1];
    // d_in[2]=src_mask (all valid), d_in[3]=dst_mask (causal) — structurally fixed
    const float* sa_wq = (const float*)d_in[4];
    const float* sa_wk = (const float*)d_in[5];
    const float* sa_wv = (const float*)d_in[6];
    const float* sa_wo = (const float*)d_in[7];
    const float* sa_bq = (const float*)d_in[8];
    const float* sa_bk = (const float*)d_in[9];
    const float* sa_bv = (const float*)d_in[10];
    const float* sa_bo = (const float*)d_in[11];
    const float* ca_wq = (const float*)d_in[12];
    const float* ca_wk = (const float*)d_in[13];
    const float* ca_wv = (const float*)d_in[14];
    const float* ca_wo = (const float*)d_in[15];
    const float* ca_bq = (const float*)d_in[16];
    const float* ca_bk = (const float*)d_in[17];
    const float* ca_bv = (const float*)d_in[18];
    const float* ca_bo = (const float*)d_in[19];
    const float* ffn_w1 = (const float*)d_in[20];
    const float* ffn_b1 = (const float*)d_in[21];
    const float* ffn_w2 = (const float*)d_in[22];
    const float* ffn_b2 = (const float*)d_in[23];
    const float* ln1g = (const float*)d_in[24];
    const float* ln1b = (const float*)d_in[25];
    const float* ln2g = (const float*)d_in[26];
    const float* ln2b = (const float*)d_in[27];
    const float* ln3g = (const float*)d_in[28];
    const float* ln3b = (const float*)d_in[29];

    char* ws = (char*)d_ws;
    size_t off = 0;
    auto alloc = [&](size_t n) { size_t o = off; off = (off + n + 255) & ~(size_t)255; return o; };

    const size_t szW = (size_t)1024 * 1024 * 2;      // 2 MB bf16 1024x1024
    short* sa_wqT = (short*)(ws + alloc(szW));
    short* sa_wkT = (short*)(ws + alloc(szW));
    short* sa_wvT = (short*)(ws + alloc(szW));
    short* sa_woT = (short*)(ws + alloc(szW));
    short* ca_wqT = (short*)(ws + alloc(szW));
    short* ca_wkT = (short*)(ws + alloc(szW));
    short* ca_wvT = (short*)(ws + alloc(szW));
    short* ca_woT = (short*)(ws + alloc(szW));
    short* w1T = (short*)(ws + alloc((size_t)4096 * 1024 * 2));
    short* w2T = (short*)(ws + alloc((size_t)1024 * 4096 * 2));
    const size_t szAct2 = (size_t)4096 * 1024 * 2;   // 8 MB bf16 activations
    const size_t szAct4 = (size_t)4096 * 1024 * 4;   // 16 MB f32 activations
    short* dstb = (short*)(ws + alloc(szAct2));
    short* srcb = (short*)(ws + alloc(szAct2));
    short* Qh = (short*)(ws + alloc(szAct2));
    short* Kh = (short*)(ws + alloc(szAct2));
    short* Vh = (short*)(ws + alloc(szAct2));
    short* VTh = (short*)(ws + alloc(szAct2));
    short* attnb = (short*)(ws + alloc(szAct2));
    float* tmp = (float*)(ws + alloc(szAct4));
    float* y1f = (float*)(ws + alloc(szAct4));
    short* y1b = (short*)(ws + alloc(szAct2));
    float* y2f = (float*)(ws + alloc(szAct4));
    short* y2b = (short*)(ws + alloc(szAct2));
    short* ffnh = (short*)(ws + alloc((size_t)4096 * 4096 * 2));

    dim3 blk(256);

    // weight prep
    wtrans<<<dim3(32, 32), blk, 0, stream>>>(sa_wq, sa_wqT, 1024, 1024);
    wtrans<<<dim3(32, 32), blk, 0, stream>>>(sa_wk, sa_wkT, 1024, 1024);
    wtrans<<<dim3(32, 32), blk, 0, stream>>>(sa_wv, sa_wvT, 1024, 1024);
    wtrans<<<dim3(32, 32), blk, 0, stream>>>(sa_wo, sa_woT, 1024, 1024);
    wtrans<<<dim3(32, 32), blk, 0, stream>>>(ca_wq, ca_wqT, 1024, 1024);
    wtrans<<<dim3(32, 32), blk, 0, stream>>>(ca_wk, ca_wkT, 1024, 1024);
    wtrans<<<dim3(32, 32), blk, 0, stream>>>(ca_wv, ca_wvT, 1024, 1024);
    wtrans<<<dim3(32, 32), blk, 0, stream>>>(ca_wo, ca_woT, 1024, 1024);
    wtrans<<<dim3(128, 32), blk, 0, stream>>>(ffn_w1, w1T, 1024, 4096);
    wtrans<<<dim3(32, 128), blk, 0, stream>>>(ffn_w2, w2T, 4096, 1024);
    conv_bf16<<<4096, blk, 0, stream>>>(dst, dstb, 1048576);
    conv_bf16<<<4096, blk, 0, stream>>>(src, srcb, 1048576);

    // ---- self-attention ----
    gemm_bt<1><<<dim3(8, 32), blk, 0, stream>>>(dstb, sa_wqT, sa_bq, Qh, 4096, 1024, 1024);
    gemm_bt<1><<<dim3(8, 32), blk, 0, stream>>>(dstb, sa_wkT, sa_bk, Kh, 4096, 1024, 1024);
    gemm_bt<1><<<dim3(8, 32), blk, 0, stream>>>(dstb, sa_wvT, sa_bv, Vh, 4096, 1024, 1024);
    transpose_v<<<dim3(16, 64), blk, 0, stream>>>(Vh, VTh, 1024);
    attn_fused<true><<<dim3(16, 64), blk, 0, stream>>>(Qh, Kh, VTh, attnb, 1024);
    gemm_bt<0><<<dim3(8, 32), blk, 0, stream>>>(attnb, sa_woT, sa_bo, tmp, 4096, 1024, 1024);
    ln_fused<<<4096, blk, 0, stream>>>(dst, tmp, ln1g, ln1b, y1f, y1b);

    // ---- cross-attention ----
    gemm_bt<1><<<dim3(8, 32), blk, 0, stream>>>(y1b, ca_wqT, ca_bq, Qh, 4096, 1024, 1024);
    gemm_bt<1><<<dim3(8, 32), blk, 0, stream>>>(srcb, ca_wkT, ca_bk, Kh, 4096, 1024, 1024);
    gemm_bt<1><<<dim3(8, 32), blk, 0, stream>>>(srcb, ca_wvT, ca_bv, Vh, 4096, 1024, 1024);
    transpose_v<<<dim3(16, 64), blk, 0, stream>>>(Vh, VTh, 1024);
    attn_fused<false><<<dim3(16, 64), blk, 0, stream>>>(Qh, Kh, VTh, attnb, 1024);
    gemm_bt<0><<<dim3(8, 32), blk, 0, stream>>>(attnb, ca_woT, ca_bo, tmp, 4096, 1024, 1024);
    ln_fused<<<4096, blk, 0, stream>>>(y1f, tmp, ln2g, ln2b, y2f, y2b);

    // ---- FFN ----
    gemm_bt<2><<<dim3(32, 32), blk, 0, stream>>>(y2b, w1T, ffn_b1, ffnh, 4096, 4096, 1024);
    gemm_bt<0><<<dim3(8, 32), blk, 0, stream>>>(ffnh, w2T, ffn_b2, tmp, 4096, 1024, 4096);
    ln_fused<<<4096, blk, 0, stream>>>(y2f, tmp, ln3g, ln3b, (float*)d_out, nullptr);

    (void)in_sizes; (void)n_in; (void)out_size; (void)ws_size;
}

// Round 2
// 624.242 us; speedup vs baseline: 1.2540x; 1.2540x over previous
//
#include <hip/hip_runtime.h>
#include <math.h>

typedef __attribute__((ext_vector_type(4))) float f32x4;
typedef __attribute__((ext_vector_type(8))) __bf16 bf16x8;
typedef __attribute__((ext_vector_type(8))) short short8;

#define DEV __device__ __forceinline__

DEV short f2bfs(float f) {
    unsigned u = __builtin_bit_cast(unsigned, f);
    unsigned r = (u + 0x7FFFu + ((u >> 16) & 1u)) >> 16;   // RNE
    return (short)r;
}

DEV f32x4 mfma16(bf16x8 a, bf16x8 b, f32x4 c) {
    return __builtin_amdgcn_mfma_f32_16x16x32_bf16(a, b, c, 0, 0, 0);
}

DEV void gload_lds16(const void* g, void* l) {
    __builtin_amdgcn_global_load_lds((const __attribute__((address_space(1))) void*)g,
                                     (__attribute__((address_space(3))) void*)l, 16, 0, 0);
}

// ---------------------------------------------------------------------------
// Weight convert+transpose: Win f32 [Kd,Nd] -> Wout bf16 [Nd,Kd]
// ---------------------------------------------------------------------------
__global__ __launch_bounds__(256) void wtrans(const float* __restrict__ Win,
                                              short* __restrict__ Wout,
                                              int Kd, int Nd) {
    __shared__ float Tt[32][33];
    const int tx = threadIdx.x & 31, ty = threadIdx.x >> 5;  // ty 0..7
    const int k0 = blockIdx.y * 32, n0 = blockIdx.x * 32;
#pragma unroll
    for (int rr = 0; rr < 4; ++rr) {
        int k = ty * 4 + rr;
        Tt[k][tx] = Win[(size_t)(k0 + k) * Nd + n0 + tx];
    }
    __syncthreads();
#pragma unroll
    for (int rr = 0; rr < 4; ++rr) {
        int n = ty * 4 + rr;
        Wout[(size_t)(n0 + n) * Kd + k0 + tx] = f2bfs(Tt[tx][n]);
    }
}

struct WPtrs { const float* p[8]; };

// 8 x (1024x1024) weights -> contiguous bf16 [8][1024][1024] transposed
__global__ __launch_bounds__(256) void wtrans8(WPtrs wp, short* __restrict__ out) {
    const float* __restrict__ Win = wp.p[blockIdx.z];
    short* __restrict__ Wout = out + (size_t)blockIdx.z * (1024 * 1024);
    __shared__ float Tt[32][33];
    const int tx = threadIdx.x & 31, ty = threadIdx.x >> 5;
    const int k0 = blockIdx.y * 32, n0 = blockIdx.x * 32;
#pragma unroll
    for (int rr = 0; rr < 4; ++rr) {
        int k = ty * 4 + rr;
        Tt[k][tx] = Win[(size_t)(k0 + k) * 1024 + n0 + tx];
    }
    __syncthreads();
#pragma unroll
    for (int rr = 0; rr < 4; ++rr) {
        int n = ty * 4 + rr;
        Wout[(size_t)(n0 + n) * 1024 + k0 + tx] = f2bfs(Tt[tx][n]);
    }
}

// f32 -> bf16 elementwise (4 per thread)
__global__ __launch_bounds__(256) void conv_bf16(const float* __restrict__ X,
                                                 short* __restrict__ Y, int n4) {
    int i = blockIdx.x * 256 + threadIdx.x;
    if (i < n4) {
        float4 v = ((const float4*)X)[i];
        short4 o;
        o.x = f2bfs(v.x); o.y = f2bfs(v.y); o.z = f2bfs(v.z); o.w = f2bfs(v.w);
        ((short4*)Y)[i] = o;
    }
}

// ---------------------------------------------------------------------------
// GEMM: A bf16 [M,K] rm, BT bf16 [N,K] rm. Tile BM x 128, BK=64, swizzled LDS.
// LDS layout: segment c (16B) of row r stored at slot ((c + r) & 7) -> frag
// ds_read_b128 start banks cover {0,4,..,28} x2 => conflict-free (2-way).
// EPI 0: f32 [M,N] + bias (o0,b0)
// EPI 1: QKV fused (N=3072): seg0->Q head(o0,b0), seg1->K head(o1,b1),
//        seg2->V^T [bh][64][1024](o2,b2). Also works for single Q (N=1024).
// EPI 2: exact-GELU bf16 [M,N] (o0,b0)
// EPI 3: KV fused (N=2048): seg0->K head(o0,b0), seg1->V^T(o1,b1)
// ---------------------------------------------------------------------------
template <int BM, int EPI>
__global__ __launch_bounds__(256) void gemm_bt(const short* __restrict__ A,
                                               const short* __restrict__ BT,
                                               const float* __restrict__ b0,
                                               const float* __restrict__ b1,
                                               const float* __restrict__ b2,
                                               void* __restrict__ o0,
                                               void* __restrict__ o1,
                                               void* __restrict__ o2,
                                               int M, int N, int K) {
    constexpr int IM = BM / 32;
    __shared__ __align__(16) short As[BM * 64];
    __shared__ __align__(16) short Bs[128 * 64];
    const int tid = threadIdx.x, lane = tid & 63, w = tid >> 6;
    const int m0 = blockIdx.y * BM, n0 = blockIdx.x * 128;
    const int wm = (w & 1) * (BM / 2), wn = (w >> 1) * 64;
    const int rl = lane & 15, rg = lane >> 4;
    f32x4 acc[IM][4] = {};
    const char* Ab = (const char*)A;
    const char* Bb = (const char*)BT;

    for (int k0 = 0; k0 < K; k0 += 64) {
        __syncthreads();
#pragma unroll
        for (int r = 0; r < BM / 32; ++r) {   // stage A: BM rows x 128 B
            int lo = (w * (BM / 32) + r) * 1024 + lane * 16;
            int row = lo >> 7, cp = (lo >> 4) & 7, c = (cp - row) & 7;
            gload_lds16(Ab + ((size_t)(m0 + row) * K + k0 + c * 8) * 2, (char*)As + lo);
        }
#pragma unroll
        for (int r = 0; r < 4; ++r) {         // stage B: 128 rows x 128 B
            int lo = (w * 4 + r) * 1024 + lane * 16;
            int row = lo >> 7, cp = (lo >> 4) & 7, c = (cp - row) & 7;
            gload_lds16(Bb + ((size_t)(n0 + row) * K + k0 + c * 8) * 2, (char*)Bs + lo);
        }
        __syncthreads();
        bf16x8 af[IM][2], bfr[4][2];
#pragma unroll
        for (int i = 0; i < IM; i++) {
            int row = wm + i * 16 + rl;
#pragma unroll
            for (int kk = 0; kk < 2; kk++)
                af[i][kk] = *(const bf16x8*)(As + row * 64 + ((((kk << 2) | rg) + row) & 7) * 8);
        }
#pragma unroll
        for (int j = 0; j < 4; j++) {
            int row = wn + j * 16 + rl;
#pragma unroll
            for (int kk = 0; kk < 2; kk++)
                bfr[j][kk] = *(const bf16x8*)(Bs + row * 64 + ((((kk << 2) | rg) + row) & 7) * 8);
        }
#pragma unroll
        for (int i = 0; i < IM; i++)
#pragma unroll
            for (int j = 0; j < 4; j++) {
                acc[i][j] = mfma16(af[i][0], bfr[j][0], acc[i][j]);
                acc[i][j] = mfma16(af[i][1], bfr[j][1], acc[i][j]);
            }
    }

#pragma unroll
    for (int i = 0; i < IM; i++) {
        int gm0 = m0 + wm + i * 16 + rg * 4;
#pragma unroll
        for (int j = 0; j < 4; j++) {
            int gn = n0 + wn + j * 16 + rl;
            if (EPI == 0) {
                float bv = b0[gn];
#pragma unroll
                for (int r = 0; r < 4; r++)
                    ((float*)o0)[(size_t)(gm0 + r) * N + gn] = acc[i][j][r] + bv;
            } else if (EPI == 2) {
                float bv = b0[gn];
#pragma unroll
                for (int r = 0; r < 4; r++) {
                    float v = acc[i][j][r] + bv;
                    float g = 0.5f * v * (1.0f + erff(v * 0.70710678118654752f));
                    ((short*)o0)[(size_t)(gm0 + r) * N + gn] = f2bfs(g);
                }
            } else {  // EPI 1 / 3: head or V^T layouts
                int seg = gn >> 10, n1 = gn & 1023, h = n1 >> 6, d = n1 & 63;
                int b = gm0 >> 10, t0 = gm0 & 1023;
                bool isV = (EPI == 1) ? (seg == 2) : (seg == 1);
                const float* bp = (EPI == 1) ? (seg == 0 ? b0 : (seg == 1 ? b1 : b2))
                                             : (seg == 0 ? b0 : b1);
                float bv = bp[n1];
                if (!isV) {
                    short* hp = (short*)((EPI == 1) ? (seg == 0 ? o0 : o1) : o0);
                    size_t base = ((size_t)(b * 16 + h) * 1024 + t0) * 64 + d;
#pragma unroll
                    for (int r = 0; r < 4; r++)
                        hp[base + (size_t)r * 64] = f2bfs(acc[i][j][r] + bv);
                } else {
                    short* vp = (short*)((EPI == 1) ? o2 : o1);
                    short4 pk;
                    pk.x = f2bfs(acc[i][j][0] + bv);
                    pk.y = f2bfs(acc[i][j][1] + bv);
                    pk.z = f2bfs(acc[i][j][2] + bv);
                    pk.w = f2bfs(acc[i][j][3] + bv);
                    *(short4*)(vp + ((size_t)(b * 16 + h) * 64 + d) * 1024 + t0) = pk;
                }
            }
        }
    }
}

// ---------------------------------------------------------------------------
// Flash attention: Qh [bh][1024][64], Kh [bh][TK][64], VTh [bh][64][TK] (bf16)
// Out bf16 [B,1024,1024]. Block = (b,h,64 Q rows), 4 waves x 16 rows.
// ---------------------------------------------------------------------------
template <bool CAUSAL>
__global__ __launch_bounds__(256) void attn_fused(const short* __restrict__ Qh,
                                                  const short* __restrict__ Kh,
                                                  const short* __restrict__ VTh,
                                                  short* __restrict__ Out, int TKn) {
    __shared__ __align__(16) short Ks[32 * 72];       // [key][d] pad 64->72
    __shared__ __align__(16) short Vts[64 * 40];      // [d][key] pad 32->40
    __shared__ __align__(16) short Ps[4 * 16 * 40];   // per-wave P, pad 32->40
    const int tid = threadIdx.x, lane = tid & 63, w = tid >> 6;
    const int rl = lane & 15, rg = lane >> 4;
    const int bh = blockIdx.y, b = bh >> 4, h = bh & 15;
    const int q0 = blockIdx.x * 64;
    const size_t qbase = (size_t)bh * 1024 * 64;
    const size_t kbase = (size_t)bh * (size_t)TKn * 64;

    bf16x8 qf[2];
    {
        int qrow = q0 + w * 16 + rl;
        qf[0] = *(const bf16x8*)(Qh + qbase + (size_t)qrow * 64 + rg * 8);
        qf[1] = *(const bf16x8*)(Qh + qbase + (size_t)qrow * 64 + 32 + rg * 8);
    }
    f32x4 o[4] = {};
    float mrow[4] = {-1e30f, -1e30f, -1e30f, -1e30f};
    float lrow[4] = {0.f, 0.f, 0.f, 0.f};

    const int nkt = CAUSAL ? (q0 >> 5) + 2 : (TKn >> 5);
    for (int kt = 0; kt < nkt; ++kt) {
        __syncthreads();
        {
            int key = tid >> 3, dg = tid & 7;
            *(bf16x8*)(Ks + key * 72 + dg * 8) =
                *(const bf16x8*)(Kh + kbase + (size_t)(kt * 32 + key) * 64 + dg * 8);
            int d = tid >> 2, kg = tid & 3;
            *(bf16x8*)(Vts + d * 40 + kg * 8) =
                *(const bf16x8*)(VTh + kbase + (size_t)d * TKn + kt * 32 + kg * 8);
        }
        __syncthreads();
        f32x4 s[2];
#pragma unroll
        for (int ch = 0; ch < 2; ++ch) {
            f32x4 z = {};
            bf16x8 kb0 = *(const bf16x8*)(Ks + (ch * 16 + rl) * 72 + rg * 8);
            bf16x8 kb1 = *(const bf16x8*)(Ks + (ch * 16 + rl) * 72 + 32 + rg * 8);
            z = mfma16(qf[0], kb0, z);
            z = mfma16(qf[1], kb1, z);
            s[ch] = z;
        }
        float alpha[4];
        short* Pw = Ps + w * 640;
#pragma unroll
        for (int r = 0; r < 4; ++r) {
            float s0 = s[0][r] * 0.125f, s1 = s[1][r] * 0.125f;
            if (CAUSAL) {
                int qr = q0 + w * 16 + rg * 4 + r;
                if (kt * 32 + rl > qr) s0 = -1e30f;
                if (kt * 32 + 16 + rl > qr) s1 = -1e30f;
            }
            float mx = fmaxf(s0, s1);
            mx = fmaxf(mx, __shfl_xor(mx, 1));
            mx = fmaxf(mx, __shfl_xor(mx, 2));
            mx = fmaxf(mx, __shfl_xor(mx, 4));
            mx = fmaxf(mx, __shfl_xor(mx, 8));
            float mn = fmaxf(mrow[r], mx);
            float al = __expf(mrow[r] - mn);
            mrow[r] = mn;
            float p0 = __expf(s0 - mn), p1 = __expf(s1 - mn);
            float rs = p0 + p1;
            rs += __shfl_xor(rs, 1);
            rs += __shfl_xor(rs, 2);
            rs += __shfl_xor(rs, 4);
            rs += __shfl_xor(rs, 8);
            lrow[r] = lrow[r] * al + rs;
            alpha[r] = al;
            Pw[(rg * 4 + r) * 40 + rl] = f2bfs(p0);
            Pw[(rg * 4 + r) * 40 + 16 + rl] = f2bfs(p1);
        }
#pragma unroll
        for (int j = 0; j < 4; j++)
#pragma unroll
            for (int r = 0; r < 4; r++) o[j][r] *= alpha[r];
        // LDS round-trip: C-layout P -> A-operand layout
        bf16x8 pa = *(const bf16x8*)(Ps + w * 640 + rl * 40 + rg * 8);
#pragma unroll
        for (int j = 0; j < 4; j++) {
            bf16x8 vb = *(const bf16x8*)(Vts + (j * 16 + rl) * 40 + rg * 8);
            o[j] = mfma16(pa, vb, o[j]);
        }
    }
    float inv[4];
#pragma unroll
    for (int r = 0; r < 4; r++) inv[r] = 1.0f / lrow[r];
#pragma unroll
    for (int j = 0; j < 4; j++) {
#pragma unroll
        for (int r = 0; r < 4; r++) {
            int row = q0 + w * 16 + rg * 4 + r;
            int col = h * 64 + j * 16 + rl;
            Out[((size_t)b * 1024 + row) * 1024 + col] = f2bfs(o[j][r] * inv[r]);
        }
    }
}

// ---------------------------------------------------------------------------
// Fused residual add + LayerNorm over C=1024. Writes f32 (+optional bf16).
// ---------------------------------------------------------------------------
__global__ __launch_bounds__(256) void ln_fused(const float* __restrict__ X,
                                                const float* __restrict__ R,
                                                const float* __restrict__ gam,
                                                const float* __restrict__ bet,
                                                float* __restrict__ Yf,
                                                short* __restrict__ Yb) {
    const int row = blockIdx.x, tid = threadIdx.x;
    const int lane = tid & 63, w = tid >> 6;
    const float* xr = X + (size_t)row * 1024;
    const float* rr = R + (size_t)row * 1024;
    float4 xv = ((const float4*)xr)[tid];
    float4 rv = ((const float4*)rr)[tid];
    float v0 = xv.x + rv.x, v1 = xv.y + rv.y, v2 = xv.z + rv.z, v3 = xv.w + rv.w;
    float s = v0 + v1 + v2 + v3;
    float ss = v0 * v0 + v1 * v1 + v2 * v2 + v3 * v3;
#pragma unroll
    for (int off = 1; off < 64; off <<= 1) {
        s += __shfl_xor(s, off);
        ss += __shfl_xor(ss, off);
    }
    __shared__ float sred[4], ssred[4];
    if (lane == 0) { sred[w] = s; ssred[w] = ss; }
    __syncthreads();
    s = sred[0] + sred[1] + sred[2] + sred[3];
    ss = ssred[0] + ssred[1] + ssred[2] + ssred[3];
    float mu = s * (1.0f / 1024.0f);
    float var = ss * (1.0f / 1024.0f) - mu * mu;
    float rsq = rsqrtf(var + 1e-12f);
    float4 gv = ((const float4*)gam)[tid];
    float4 bv = ((const float4*)bet)[tid];
    float y0 = (v0 - mu) * rsq * gv.x + bv.x;
    float y1 = (v1 - mu) * rsq * gv.y + bv.y;
    float y2 = (v2 - mu) * rsq * gv.z + bv.z;
    float y3 = (v3 - mu) * rsq * gv.w + bv.w;
    float4 yo = {y0, y1, y2, y3};
    ((float4*)(Yf + (size_t)row * 1024))[tid] = yo;
    if (Yb) {
        short4 ob;
        ob.x = f2bfs(y0); ob.y = f2bfs(y1); ob.z = f2bfs(y2); ob.w = f2bfs(y3);
        ((short4*)(Yb + (size_t)row * 1024))[tid] = ob;
    }
}

// ---------------------------------------------------------------------------
extern "C" void kernel_launch(void* const* d_in, const int* in_sizes, int n_in,
                              void* d_out, int out_size, void* d_ws, size_t ws_size,
                              hipStream_t stream) {
    const float* src = (const float*)d_in[0];
    const float* dst = (const float*)d_in[1];
    // d_in[2]=src_mask (all valid), d_in[3]=dst_mask (causal) — structurally fixed
    const float* sa_wq = (const float*)d_in[4];
    const float* sa_wk = (const float*)d_in[5];
    const float* sa_wv = (const float*)d_in[6];
    const float* sa_wo = (const float*)d_in[7];
    const float* sa_bq = (const float*)d_in[8];
    const float* sa_bk = (const float*)d_in[9];
    const float* sa_bv = (const float*)d_in[10];
    const float* sa_bo = (const float*)d_in[11];
    const float* ca_wq = (const float*)d_in[12];
    const float* ca_wk = (const float*)d_in[13];
    const float* ca_wv = (const float*)d_in[14];
    const float* ca_wo = (const float*)d_in[15];
    const float* ca_bq = (const float*)d_in[16];
    const float* ca_bk = (const float*)d_in[17];
    const float* ca_bv = (const float*)d_in[18];
    const float* ca_bo = (const float*)d_in[19];
    const float* ffn_w1 = (const float*)d_in[20];
    const float* ffn_b1 = (const float*)d_in[21];
    const float* ffn_w2 = (const float*)d_in[22];
    const float* ffn_b2 = (const float*)d_in[23];
    const float* ln1g = (const float*)d_in[24];
    const float* ln1b = (const float*)d_in[25];
    const float* ln2g = (const float*)d_in[26];
    const float* ln2b = (const float*)d_in[27];
    const float* ln3g = (const float*)d_in[28];
    const float* ln3b = (const float*)d_in[29];

    char* ws = (char*)d_ws;
    size_t off = 0;
    auto alloc = [&](size_t n) { size_t o = off; off = (off + n + 255) & ~(size_t)255; return o; };

    const size_t szW = (size_t)1024 * 1024 * 2;      // 2 MB bf16 1024x1024
    short* wT = (short*)(ws + alloc(8 * szW));       // 8 transposed attn weights
    short* w1T = (short*)(ws + alloc((size_t)4096 * 1024 * 2));
    short* w2T = (short*)(ws + alloc((size_t)1024 * 4096 * 2));
    const size_t szAct2 = (size_t)4096 * 1024 * 2;   // 8 MB bf16 activations
    const size_t szAct4 = (size_t)4096 * 1024 * 4;   // 16 MB f32 activations
    short* dstb = (short*)(ws + alloc(szAct2));
    short* srcb = (short*)(ws + alloc(szAct2));
    short* Qh = (short*)(ws + alloc(szAct2));
    short* Kh = (short*)(ws + alloc(szAct2));
    short* VTh = (short*)(ws + alloc(szAct2));
    short* attnb = (short*)(ws + alloc(szAct2));
    float* tmp = (float*)(ws + alloc(szAct4));
    float* y1f = (float*)(ws + alloc(szAct4));
    short* y1b = (short*)(ws + alloc(szAct2));
    float* y2f = (float*)(ws + alloc(szAct4));
    short* y2b = (short*)(ws + alloc(szAct2));
    short* ffnh = (short*)(ws + alloc((size_t)4096 * 4096 * 2));

    // transposed-weight views (order matches WPtrs below)
    short* sa_wqkvT = wT;                 // rows 0..3071 = wq^T, wk^T, wv^T
    short* sa_woT = wT + 3 * (size_t)1048576;
    short* ca_wqT = wT + 4 * (size_t)1048576;
    short* ca_wkvT = wT + 5 * (size_t)1048576;  // rows 0..2047 = wk^T, wv^T
    short* ca_woT = wT + 7 * (size_t)1048576;

    dim3 blk(256);

    // weight prep
    WPtrs wp = {{sa_wq, sa_wk, sa_wv, sa_wo, ca_wq, ca_wk, ca_wv, ca_wo}};
    wtrans8<<<dim3(32, 32, 8), blk, 0, stream>>>(wp, wT);
    wtrans<<<dim3(128, 32), blk, 0, stream>>>(ffn_w1, w1T, 1024, 4096);
    wtrans<<<dim3(32, 128), blk, 0, stream>>>(ffn_w2, w2T, 4096, 1024);
    conv_bf16<<<4096, blk, 0, stream>>>(dst, dstb, 1048576);
    conv_bf16<<<4096, blk, 0, stream>>>(src, srcb, 1048576);

    // ---- self-attention ----
    gemm_bt<128, 1><<<dim3(24, 32), blk, 0, stream>>>(dstb, sa_wqkvT, sa_bq, sa_bk, sa_bv,
                                                      Qh, Kh, VTh, 4096, 3072, 1024);
    attn_fused<true><<<dim3(16, 64), blk, 0, stream>>>(Qh, Kh, VTh, attnb, 1024);
    gemm_bt<64, 0><<<dim3(8, 64), blk, 0, stream>>>(attnb, sa_woT, sa_bo, nullptr, nullptr,
                                                    tmp, nullptr, nullptr, 4096, 1024, 1024);
    ln_fused<<<4096, blk, 0, stream>>>(dst, tmp, ln1g, ln1b, y1f, y1b);

    // ---- cross-attention ----
    gemm_bt<64, 1><<<dim3(8, 64), blk, 0, stream>>>(y1b, ca_wqT, ca_bq, nullptr, nullptr,
                                                    Qh, nullptr, nullptr, 4096, 1024, 1024);
    gemm_bt<128, 3><<<dim3(16, 32), blk, 0, stream>>>(srcb, ca_wkvT, ca_bk, ca_bv, nullptr,
                                                      Kh, VTh, nullptr, 4096, 2048, 1024);
    attn_fused<false><<<dim3(16, 64), blk, 0, stream>>>(Qh, Kh, VTh, attnb, 1024);
    gemm_bt<64, 0><<<dim3(8, 64), blk, 0, stream>>>(attnb, ca_woT, ca_bo, nullptr, nullptr,
                                                    tmp, nullptr, nullptr, 4096, 1024, 1024);
    ln_fused<<<4096, blk, 0, stream>>>(y1f, tmp, ln2g, ln2b, y2f, y2b);

    // ---- FFN ----
    gemm_bt<128, 2><<<dim3(32, 32), blk, 0, stream>>>(y2b, w1T, ffn_b1, nullptr, nullptr,
                                                      ffnh, nullptr, nullptr, 4096, 4096, 1024);
    gemm_bt<64, 0><<<dim3(8, 64), blk, 0, stream>>>(ffnh, w2T, ffn_b2, nullptr, nullptr,
                                                    tmp, nullptr, nullptr, 4096, 1024, 4096);
    ln_fused<<<4096, blk, 0, stream>>>(y2f, tmp, ln3g, ln3b, (float*)d_out, nullptr);

    (void)in_sizes; (void)n_in; (void)out_size; (void)ws_size;
}